// Round 2
// baseline (2145.593 us; speedup 1.0000x reference)
//
#include <hip/hip_runtime.h>

constexpr int Nn  = 100000;  // nodes
constexpr int Rr  = 4;       // relations
constexpr int Ee  = 200000;  // edges per relation
constexpr int Din = 128;     // input feat dim
constexpr int Dh  = 256;     // hidden/output dim
constexpr int RN  = Rr * Nn; // 400000
constexpr int RE  = Rr * Ee; // 800000

typedef float  f32x4  __attribute__((ext_vector_type(4)));
typedef __bf16 bf16x4 __attribute__((ext_vector_type(4)));
typedef __bf16 bf16x8 __attribute__((ext_vector_type(8)));

// ---------------------------------------------------------------- degrees
__global__ __launch_bounds__(256) void count_deg_kernel(
    const int* __restrict__ src, const int* __restrict__ dst,
    int* __restrict__ dego, int* __restrict__ degi) {
  int i = blockIdx.x * 256 + threadIdx.x;
  if (i < RE) {
    int r = i / Ee;
    atomicAdd(&dego[r * Nn + src[i]], 1);
    atomicAdd(&degi[r * Nn + dst[i]], 1);
  }
}

__global__ __launch_bounds__(256) void norms_kernel(
    const int* __restrict__ dego, const int* __restrict__ degi,
    float* __restrict__ ns, float* __restrict__ nd) {
  int i = blockIdx.x * 256 + threadIdx.x;
  if (i < RN) {
    int a = dego[i]; if (a < 1) a = 1;
    int b = degi[i]; if (b < 1) b = 1;
    ns[i] = rsqrtf((float)a);
    nd[i] = rsqrtf((float)b);
  }
}

// ---------------------------------------------------------------- scan
__device__ inline int block_excl_scan_256(int tsum, int tid, int* wsum) {
  int lane = tid & 63, w = tid >> 6;
  int inc = tsum;
#pragma unroll
  for (int off = 1; off < 64; off <<= 1) {
    int t = __shfl_up(inc, off);
    if (lane >= off) inc += t;
  }
  if (lane == 63) wsum[w] = inc;
  __syncthreads();
  int woff = 0;
  for (int i = 0; i < w; ++i) woff += wsum[i];
  return woff + inc - tsum;
}

__global__ __launch_bounds__(256) void scan1_kernel(
    const int* __restrict__ in, int* __restrict__ out,
    int* __restrict__ partials, int n) {
  __shared__ int wsum[4];
  int tid = threadIdx.x;
  int base = blockIdx.x * 1024 + tid * 4;
  int v[4];
#pragma unroll
  for (int j = 0; j < 4; ++j) v[j] = (base + j < n) ? in[base + j] : 0;
  int tsum = v[0] + v[1] + v[2] + v[3];
  int off = block_excl_scan_256(tsum, tid, wsum);
  int run = off;
#pragma unroll
  for (int j = 0; j < 4; ++j) {
    if (base + j < n) out[base + j] = run;
    run += v[j];
  }
  __syncthreads();
  if (tid == 0) partials[blockIdx.x] = wsum[0] + wsum[1] + wsum[2] + wsum[3];
}

__global__ __launch_bounds__(256) void scan2_kernel(int* __restrict__ p, int n) {
  __shared__ int wsum[4];
  int tid = threadIdx.x;
  int e0 = (2 * tid     < n) ? p[2 * tid]     : 0;
  int e1 = (2 * tid + 1 < n) ? p[2 * tid + 1] : 0;
  int off = block_excl_scan_256(e0 + e1, tid, wsum);
  if (2 * tid     < n) p[2 * tid]     = off;
  if (2 * tid + 1 < n) p[2 * tid + 1] = off + e0;
}

__global__ __launch_bounds__(256) void scan3_kernel(
    int* __restrict__ out, const int* __restrict__ partials, int n) {
  int i = blockIdx.x * 256 + threadIdx.x;
  if (i < n) out[i] += partials[i >> 10];
  if (i == 0) out[n] = RE;
}

__global__ __launch_bounds__(256) void fill_eid_kernel(
    const int* __restrict__ dst, int* __restrict__ cursor,
    int* __restrict__ eid) {
  int i = blockIdx.x * 256 + threadIdx.x;
  if (i < RE) {
    int r = i / Ee;
    int pos = atomicAdd(&cursor[r * Nn + dst[i]], 1);
    eid[pos] = i;
  }
}

// ---------------------------------------------- combined bias: 0.25*sum_r b_r
__global__ __launch_bounds__(256) void bias_combine_kernel(
    const float* __restrict__ b1, const float* __restrict__ b2,
    float* __restrict__ cb) {
  int i = threadIdx.x;
  cb[i]      = 0.25f * (b1[i] + b1[Dh + i] + b1[2 * Dh + i] + b1[3 * Dh + i]);
  cb[Dh + i] = 0.25f * (b2[i] + b2[Dh + i] + b2[2 * Dh + i] + b2[3 * Dh + i]);
}

// ------------------------------------- weight pre-transpose: [K][256]f32 ->
// [256][K]bf16 so GEMM B fragments are contiguous 16B loads per lane
__global__ __launch_bounds__(256) void transpose_bf16_kernel(
    const float* __restrict__ in, __bf16* __restrict__ outp, int K) {
  __shared__ float t[32][33];
  int kb = blockIdx.x * 32, nb = blockIdx.y * 32;
  int tx = threadIdx.x & 31, ty = threadIdx.x >> 5;  // 32x8
#pragma unroll
  for (int j = 0; j < 32; j += 8)
    t[ty + j][tx] = in[(size_t)(kb + ty + j) * Dh + nb + tx];
  __syncthreads();
#pragma unroll
  for (int j = 0; j < 32; j += 8)
    outp[(size_t)(nb + ty + j) * K + kb + tx] = (__bf16)t[tx][ty + j];
}

// ---------------------------------------------------------------- GEMM
// Barrier-free register-streaming GEMM: C[M,256] = alpha*A[M,K]@B[K,256]+bias.
// Block = 64 rows x 256 cols; wave w owns cols [w*64, w*64+64).
// A fragments are loaded directly from global in MFMA layout (lane l15 = row,
// quad*8 = k offset, 16B contiguous per lane); the 4 waves share A via L1.
// B (pre-transposed bf16 [256][K]) is L2-resident. No LDS, no __syncthreads.
template <int K, bool ABF16, bool OUT_BF16>
__global__ __launch_bounds__(256) void gemm_stream(
    const void* __restrict__ Av, const __bf16* __restrict__ Bt,
    void* __restrict__ Cv, const float* __restrict__ bias,
    float alpha, int M) {
  const int tid  = threadIdx.x;
  const int w    = tid >> 6;
  const int lane = tid & 63;
  const int l15  = lane & 15, quad = lane >> 4;
  const int m0   = blockIdx.x * 64;
  const int n0   = w * 64;

  f32x4 acc[4][4] = {};

  int arow[4];
#pragma unroll
  for (int mt = 0; mt < 4; ++mt) {
    int r = m0 + mt * 16 + l15;
    arow[mt] = (r < M) ? r : (M - 1);  // clamp: OOB rows read row M-1, stores guarded
  }

#pragma unroll 4
  for (int kt = 0; kt < K / 32; ++kt) {
    const int kk = kt * 32 + quad * 8;
    bf16x8 bfrag[4];
#pragma unroll
    for (int nt = 0; nt < 4; ++nt) {
      int n = n0 + nt * 16 + l15;
      bfrag[nt] = *(const bf16x8*)(Bt + (size_t)n * K + kk);
    }
    bf16x8 afrag[4];
    if constexpr (ABF16) {
      const __bf16* A = (const __bf16*)Av;
#pragma unroll
      for (int mt = 0; mt < 4; ++mt)
        afrag[mt] = *(const bf16x8*)(A + (size_t)arow[mt] * K + kk);
    } else {
      const float* A = (const float*)Av;
#pragma unroll
      for (int mt = 0; mt < 4; ++mt) {
        const float* ap = A + (size_t)arow[mt] * K + kk;
        f32x4 v0 = *(const f32x4*)(ap);
        f32x4 v1 = *(const f32x4*)(ap + 4);
        bf16x8 t;
        t[0] = (__bf16)v0[0]; t[1] = (__bf16)v0[1];
        t[2] = (__bf16)v0[2]; t[3] = (__bf16)v0[3];
        t[4] = (__bf16)v1[0]; t[5] = (__bf16)v1[1];
        t[6] = (__bf16)v1[2]; t[7] = (__bf16)v1[3];
        afrag[mt] = t;
      }
    }
#pragma unroll
    for (int mt = 0; mt < 4; ++mt)
#pragma unroll
      for (int nt = 0; nt < 4; ++nt)
        acc[mt][nt] = __builtin_amdgcn_mfma_f32_16x16x32_bf16(
            afrag[mt], bfrag[nt], acc[mt][nt], 0, 0, 0);
  }

#pragma unroll
  for (int mt = 0; mt < 4; ++mt) {
    int rl = m0 + mt * 16 + quad * 4;
#pragma unroll
    for (int nt = 0; nt < 4; ++nt) {
      int col = n0 + nt * 16 + l15;
      float bv = bias ? bias[col] : 0.f;
#pragma unroll
      for (int ri = 0; ri < 4; ++ri) {
        int grow = rl + ri;
        if (grow < M) {
          size_t idx = (size_t)grow * Dh + col;
          float v = alpha * acc[mt][nt][ri] + bv;
          if constexpr (OUT_BF16) {
            ((__bf16*)Cv)[idx] = (__bf16)v;
          } else {
            ((float*)Cv)[idx] = v;
          }
        }
      }
    }
  }
}

// ------------------------------------------------------------- CSR aggregate
// one wave per (relation, dst node); 2-edge software pipeline to overlap the
// eid->src->x/ew dependent-load chain (avg degree = 2). Writes nd-scaled bf16
// into the fused [N][4*Dh] panel.
__global__ __launch_bounds__(256) void aggregate4_kernel(
    const float* __restrict__ x, const __bf16* __restrict__ ew,
    const int* __restrict__ src, const int* __restrict__ rowptr,
    const int* __restrict__ eid, const float* __restrict__ ns,
    const float* __restrict__ nd, __bf16* __restrict__ agg4) {
  int g = blockIdx.x * 4 + (threadIdx.x >> 6);
  if (g >= RN) return;
  int r = g / Nn;
  int n = g - r * Nn;
  int lane = threadIdx.x & 63;
  int p0 = rowptr[g], p1 = rowptr[g + 1];
  const float* nsr = ns + (size_t)r * Nn;
  f32x4 acc = {0.f, 0.f, 0.f, 0.f};
  for (int p = p0; p < p1; p += 2) {
    int  geA  = eid[p];
    bool hasB = (p + 1 < p1);
    int  geB  = hasB ? eid[p + 1] : geA;
    int sA = src[geA];
    int sB = src[geB];
    float scA = nsr[sA];
    float scB = hasB ? nsr[sB] : 0.f;
    f32x4  xA = *(const f32x4*)(x + (size_t)sA * Dh + lane * 4);
    bf16x4 eA = *(const bf16x4*)(ew + (size_t)geA * Dh + lane * 4);
    f32x4  xB = *(const f32x4*)(x + (size_t)sB * Dh + lane * 4);
    bf16x4 eB = *(const bf16x4*)(ew + (size_t)geB * Dh + lane * 4);
    acc[0] += xA[0] * scA * (float)eA[0] + xB[0] * scB * (float)eB[0];
    acc[1] += xA[1] * scA * (float)eA[1] + xB[1] * scB * (float)eB[1];
    acc[2] += xA[2] * scA * (float)eA[2] + xB[2] * scB * (float)eB[2];
    acc[3] += xA[3] * scA * (float)eA[3] + xB[3] * scB * (float)eB[3];
  }
  float ndv = nd[g];
  bf16x4 o;
  o[0] = (__bf16)(acc[0] * ndv);
  o[1] = (__bf16)(acc[1] * ndv);
  o[2] = (__bf16)(acc[2] * ndv);
  o[3] = (__bf16)(acc[3] * ndv);
  *(bf16x4*)(agg4 + (size_t)n * (4 * Dh) + (size_t)r * Dh + lane * 4) = o;
}

// ------------------------------------- fallback atomic scatter (chunked ws)
__global__ __launch_bounds__(256) void edge_scatter_kernel(
    const float* __restrict__ x, const __bf16* __restrict__ ew,
    const int* __restrict__ src, const int* __restrict__ dst,
    const float* __restrict__ ns, const float* __restrict__ nd,
    float* __restrict__ aggf, int cnt) {
  int e = blockIdx.x * 4 + (threadIdx.x >> 6);
  if (e >= cnt) return;
  int lane = threadIdx.x & 63;
  int s = src[e], d = dst[e];
  float sc = ns[s] * nd[d];
  f32x4 xv = *(const f32x4*)(x + (size_t)s * Dh + lane * 4);
  bf16x4 ev = *(const bf16x4*)(ew + (size_t)e * Dh + lane * 4);
  float* ap = aggf + (size_t)d * Dh + lane * 4;
  atomicAdd(ap + 0, xv[0] * sc * (float)ev[0]);
  atomicAdd(ap + 1, xv[1] * sc * (float)ev[1]);
  atomicAdd(ap + 2, xv[2] * sc * (float)ev[2]);
  atomicAdd(ap + 3, xv[3] * sc * (float)ev[3]);
}

__global__ __launch_bounds__(256) void pack_agg_kernel(
    const float* __restrict__ aggf, __bf16* __restrict__ agg4, int r) {
  int i = blockIdx.x * 256 + threadIdx.x;  // over Nn*64 f32x4 groups
  if (i < Nn * 64) {
    int n = i >> 6;
    int c = (i & 63) * 4;
    f32x4 v = *(const f32x4*)(aggf + (size_t)n * Dh + c);
    bf16x4 o;
    o[0] = (__bf16)v[0]; o[1] = (__bf16)v[1];
    o[2] = (__bf16)v[2]; o[3] = (__bf16)v[3];
    *(bf16x4*)(agg4 + (size_t)n * (4 * Dh) + (size_t)r * Dh + c) = o;
  }
}

// ---------------------------------------------------------------- launch
extern "C" void kernel_launch(void* const* d_in, const int* in_sizes, int n_in,
                              void* d_out, int out_size, void* d_ws, size_t ws_size,
                              hipStream_t stream) {
  const float* node_feat  = (const float*)d_in[0];
  const float* edge_w_raw = (const float*)d_in[1];
  const int*   src        = (const int*)d_in[2];
  const int*   dst        = (const int*)d_in[3];
  const float* Wn = (const float*)d_in[4];
  const float* bn = (const float*)d_in[5];
  const float* Wr = (const float*)d_in[6];
  const float* br = (const float*)d_in[7];
  const float* W1 = (const float*)d_in[8];
  const float* b1 = (const float*)d_in[9];
  const float* W2 = (const float*)d_in[10];
  const float* b2 = (const float*)d_in[11];
  float* out = (float*)d_out;

  char* ws = (char*)d_ws;
  size_t off = 0;
  auto alloc = [&](size_t bytes) -> void* {
    void* p = ws + off;
    off += (bytes + 255) & ~(size_t)255;
    return p;
  };
  float*  ns     = (float*)alloc(sizeof(float) * RN);
  float*  nd     = (float*)alloc(sizeof(float) * RN);
  int*    rowptr = (int*)alloc(sizeof(int) * (RN + 1));
  int*    cursor = (int*)alloc(sizeof(int) * RN);
  int*    eid    = (int*)alloc(sizeof(int) * RE);
  int*    parts  = (int*)alloc(sizeof(int) * 512);
  float*  cb     = (float*)alloc(sizeof(float) * 2 * Dh);
  __bf16* BtWn   = (__bf16*)alloc(sizeof(__bf16) * (size_t)Din * Dh);
  __bf16* BtWr   = (__bf16*)alloc(sizeof(__bf16) * (size_t)Din * Dh);
  __bf16* BtW1   = (__bf16*)alloc(sizeof(__bf16) * (size_t)(4 * Dh) * Dh);
  __bf16* BtW2   = (__bf16*)alloc(sizeof(__bf16) * (size_t)(4 * Dh) * Dh);
  float*  x0     = (float*)alloc(sizeof(float) * (size_t)Nn * Dh);
  float*  h1     = (float*)alloc(sizeof(float) * (size_t)Nn * Dh);
  __bf16* agg4   = (__bf16*)alloc(sizeof(__bf16) * (size_t)Nn * 4 * Dh);
  size_t fixed = off;
  size_t ew_full_bytes = (size_t)RE * Dh * 2;
  bool full = (fixed + ew_full_bytes) <= ws_size;
  __bf16* ewb  = nullptr;
  float*  aggf = nullptr;
  int CH = Ee;
  if (full) {
    ewb = (__bf16*)alloc(ew_full_bytes);
  } else {
    aggf = (float*)alloc(sizeof(float) * (size_t)Nn * Dh);
    size_t avail = ws_size > off ? ws_size - off : 0;
    size_t ch = avail / ((size_t)Dh * 2);
    ch = (ch / 512) * 512;
    if (ch > (size_t)Ee) ch = (size_t)Ee;
    if (ch < 512) ch = 512;
    CH = (int)ch;
    ewb = (__bf16*)alloc((size_t)CH * Dh * 2);
  }

  // degrees live temporarily in agg4 (3.2 MB << 204.8 MB)
  int* dego = (int*)agg4;
  int* degi = dego + RN;
  hipMemsetAsync(dego, 0, sizeof(int) * 2 * (size_t)RN, stream);
  count_deg_kernel<<<(RE + 255) / 256, 256, 0, stream>>>(src, dst, dego, degi);
  norms_kernel<<<(RN + 255) / 256, 256, 0, stream>>>(dego, degi, ns, nd);

  // CSR build (shared by both layers)
  int nchunks = (RN + 1023) / 1024;  // 391
  scan1_kernel<<<nchunks, 256, 0, stream>>>(degi, rowptr, parts, RN);
  scan2_kernel<<<1, 256, 0, stream>>>(parts, nchunks);
  scan3_kernel<<<(RN + 255) / 256, 256, 0, stream>>>(rowptr, parts, RN);
  hipMemcpyAsync(cursor, rowptr, sizeof(int) * RN, hipMemcpyDeviceToDevice, stream);
  fill_eid_kernel<<<(RE + 255) / 256, 256, 0, stream>>>(dst, cursor, eid);

  // small prep: combined biases + weight transposes (bf16 [256][K])
  bias_combine_kernel<<<1, 256, 0, stream>>>(b1, b2, cb);
  transpose_bf16_kernel<<<dim3(Din / 32, Dh / 32), 256, 0, stream>>>(Wn, BtWn, Din);
  transpose_bf16_kernel<<<dim3(Din / 32, Dh / 32), 256, 0, stream>>>(Wr, BtWr, Din);
  transpose_bf16_kernel<<<dim3(4 * Dh / 32, Dh / 32), 256, 0, stream>>>(W1, BtW1, 4 * Dh);
  transpose_bf16_kernel<<<dim3(4 * Dh / 32, Dh / 32), 256, 0, stream>>>(W2, BtW2, 4 * Dh);

  // x0 = node_feat @ Wn + bn
  gemm_stream<Din, false, false><<<(Nn + 63) / 64, 256, 0, stream>>>(
      node_feat, BtWn, x0, bn, 1.0f, Nn);

  // ew = edge_w_raw @ Wr + br  (all 4 relations in one M=800000 launch)
  if (full) {
    gemm_stream<Din, false, true><<<RE / 64, 256, 0, stream>>>(
        edge_w_raw, BtWr, ewb, br, 1.0f, RE);
  }

  for (int layer = 0; layer < 2; ++layer) {
    const float*  x   = layer ? h1 : x0;
    float*        o   = layer ? out : h1;
    const __bf16* Bt  = layer ? BtW2 : BtW1;
    const float*  cbl = cb + layer * Dh;
    if (full) {
      aggregate4_kernel<<<(RN + 3) / 4, 256, 0, stream>>>(
          x, ewb, src, rowptr, eid, ns, nd, agg4);
    } else {
      for (int r = 0; r < Rr; ++r) {
        hipMemsetAsync(aggf, 0, sizeof(float) * (size_t)Nn * Dh, stream);
        for (int c0 = 0; c0 < Ee; c0 += CH) {
          int cnt = (Ee - c0 < CH) ? (Ee - c0) : CH;
          gemm_stream<Din, false, true><<<(cnt + 63) / 64, 256, 0, stream>>>(
              edge_w_raw + ((size_t)r * Ee + c0) * Din, BtWr, ewb, br, 1.0f, cnt);
          edge_scatter_kernel<<<(cnt + 3) / 4, 256, 0, stream>>>(
              x, ewb, src + (size_t)r * Ee + c0, dst + (size_t)r * Ee + c0,
              ns + (size_t)r * Nn, nd + (size_t)r * Nn, aggf, cnt);
        }
        pack_agg_kernel<<<(Nn * 64 + 255) / 256, 256, 0, stream>>>(aggf, agg4, r);
      }
    }
    // o = 0.25 * agg4 @ [W_r stacked] + 0.25*sum_r b_r   (single K=1024 GEMM)
    gemm_stream<4 * Dh, true, false><<<(Nn + 63) / 64, 256, 0, stream>>>(
        agg4, Bt, o, cbl, 0.25f, Nn);
  }
}

// Round 3
// 1818.947 us; speedup vs baseline: 1.1796x; 1.1796x over previous
//
#include <hip/hip_runtime.h>

constexpr int Nn  = 100000;  // nodes
constexpr int Rr  = 4;       // relations
constexpr int Ee  = 200000;  // edges per relation
constexpr int Din = 128;     // input feat dim
constexpr int Dh  = 256;     // hidden/output dim
constexpr int RN  = Rr * Nn; // 400000
constexpr int RE  = Rr * Ee; // 800000

typedef float  f32x4  __attribute__((ext_vector_type(4)));
typedef __bf16 bf16x4 __attribute__((ext_vector_type(4)));
typedef __bf16 bf16x8 __attribute__((ext_vector_type(8)));

// ---------------------------------------------------------------- degrees
__global__ __launch_bounds__(256) void count_deg_kernel(
    const int* __restrict__ src, const int* __restrict__ dst,
    int* __restrict__ dego, int* __restrict__ degi) {
  int i = blockIdx.x * 256 + threadIdx.x;
  if (i < RE) {
    int r = i / Ee;
    atomicAdd(&dego[r * Nn + src[i]], 1);
    atomicAdd(&degi[r * Nn + dst[i]], 1);
  }
}

__global__ __launch_bounds__(256) void norms_kernel(
    const int* __restrict__ dego, const int* __restrict__ degi,
    float* __restrict__ ns, float* __restrict__ nd) {
  int i = blockIdx.x * 256 + threadIdx.x;
  if (i < RN) {
    int a = dego[i]; if (a < 1) a = 1;
    int b = degi[i]; if (b < 1) b = 1;
    ns[i] = rsqrtf((float)a);
    nd[i] = rsqrtf((float)b);
  }
}

// ---------------------------------------------------------------- scan
__device__ inline int block_excl_scan_256(int tsum, int tid, int* wsum) {
  int lane = tid & 63, w = tid >> 6;
  int inc = tsum;
#pragma unroll
  for (int off = 1; off < 64; off <<= 1) {
    int t = __shfl_up(inc, off);
    if (lane >= off) inc += t;
  }
  if (lane == 63) wsum[w] = inc;
  __syncthreads();
  int woff = 0;
  for (int i = 0; i < w; ++i) woff += wsum[i];
  return woff + inc - tsum;
}

__global__ __launch_bounds__(256) void scan1_kernel(
    const int* __restrict__ in, int* __restrict__ out,
    int* __restrict__ partials, int n) {
  __shared__ int wsum[4];
  int tid = threadIdx.x;
  int base = blockIdx.x * 1024 + tid * 4;
  int v[4];
#pragma unroll
  for (int j = 0; j < 4; ++j) v[j] = (base + j < n) ? in[base + j] : 0;
  int tsum = v[0] + v[1] + v[2] + v[3];
  int off = block_excl_scan_256(tsum, tid, wsum);
  int run = off;
#pragma unroll
  for (int j = 0; j < 4; ++j) {
    if (base + j < n) out[base + j] = run;
    run += v[j];
  }
  __syncthreads();
  if (tid == 0) partials[blockIdx.x] = wsum[0] + wsum[1] + wsum[2] + wsum[3];
}

__global__ __launch_bounds__(256) void scan2_kernel(int* __restrict__ p, int n) {
  __shared__ int wsum[4];
  int tid = threadIdx.x;
  int e0 = (2 * tid     < n) ? p[2 * tid]     : 0;
  int e1 = (2 * tid + 1 < n) ? p[2 * tid + 1] : 0;
  int off = block_excl_scan_256(e0 + e1, tid, wsum);
  if (2 * tid     < n) p[2 * tid]     = off;
  if (2 * tid + 1 < n) p[2 * tid + 1] = off + e0;
}

__global__ __launch_bounds__(256) void scan3_kernel(
    int* __restrict__ out, const int* __restrict__ partials, int n) {
  int i = blockIdx.x * 256 + threadIdx.x;
  if (i < n) out[i] += partials[i >> 10];
  if (i == 0) out[n] = RE;
}

__global__ __launch_bounds__(256) void fill_eid_kernel(
    const int* __restrict__ dst, int* __restrict__ cursor,
    int* __restrict__ eid) {
  int i = blockIdx.x * 256 + threadIdx.x;
  if (i < RE) {
    int r = i / Ee;
    int pos = atomicAdd(&cursor[r * Nn + dst[i]], 1);
    eid[pos] = i;
  }
}

// ---------------------------------------------- combined bias: 0.25*sum_r b_r
__global__ __launch_bounds__(256) void bias_combine_kernel(
    const float* __restrict__ b1, const float* __restrict__ b2,
    float* __restrict__ cb) {
  int i = threadIdx.x;
  cb[i]      = 0.25f * (b1[i] + b1[Dh + i] + b1[2 * Dh + i] + b1[3 * Dh + i]);
  cb[Dh + i] = 0.25f * (b2[i] + b2[Dh + i] + b2[2 * Dh + i] + b2[3 * Dh + i]);
}

// ------------------------------------- weight pre-transpose: [K][256]f32 ->
// [256][K]bf16 so GEMM B fragments are contiguous 16B loads per lane
__global__ __launch_bounds__(256) void transpose_bf16_kernel(
    const float* __restrict__ in, __bf16* __restrict__ outp, int K) {
  __shared__ float t[32][33];
  int kb = blockIdx.x * 32, nb = blockIdx.y * 32;
  int tx = threadIdx.x & 31, ty = threadIdx.x >> 5;  // 32x8
#pragma unroll
  for (int j = 0; j < 32; j += 8)
    t[ty + j][tx] = in[(size_t)(kb + ty + j) * Dh + nb + tx];
  __syncthreads();
#pragma unroll
  for (int j = 0; j < 32; j += 8)
    outp[(size_t)(nb + ty + j) * K + kb + tx] = (__bf16)t[tx][ty + j];
}

// ---------------------------------------------------------------- GEMM
// Pipelined global_load_lds GEMM. Block = 64 rows x 256 cols (wave w owns
// cols w*64..w*64+63). A-tiles are staged to LDS via global_load_lds(16B)
// with a both-sides XOR swizzle (off ^ ((row&7)<<4)) so ds_read_b128
// fragment reads are ~2-way conflict-free. Double-buffered with raw
// s_barrier + counted s_waitcnt vmcnt(G): next tile's stage loads stay in
// flight while current tile's MFMAs run (no __syncthreads vmcnt(0) drain).
//   !ABF16 (K=128, f32 A): grid-stride pipeline over M-tiles, full-K stage
//   ABF16  (K=1024, bf16 A): per-block M-tile, pipeline over 8 K-steps
typedef __attribute__((address_space(1))) const void* gas_p;
typedef __attribute__((address_space(3))) void* las_p;

__device__ inline void gload_lds16(const void* g, void* l) {
  __builtin_amdgcn_global_load_lds((gas_p)g, (las_p)l, 16, 0, 0);
}

__device__ inline void barrier_sync() {
  asm volatile("" ::: "memory");
  __builtin_amdgcn_s_barrier();
  __builtin_amdgcn_sched_barrier(0);
  asm volatile("" ::: "memory");
}

template <int K, bool ABF16, bool OUT_BF16>
__global__ __launch_bounds__(256, 2) void gemm_pipe(
    const void* __restrict__ Av, const __bf16* __restrict__ Bt,
    void* __restrict__ Cv, const float* __restrict__ bias,
    float alpha, int M, int mtiles) {
  constexpr int BUFB = ABF16 ? 16384 : 32768;  // staged bytes: 64r x 128k
  constexpr int ROWB = ABF16 ? 256 : 512;      // staged row bytes
  constexpr int EB   = ABF16 ? 2 : 4;
  constexpr int G    = BUFB / (256 * 16);      // gload_lds per thread
  __shared__ __align__(16) char smem[2][BUFB];
  const int tid  = threadIdx.x;
  const int w    = tid >> 6;
  const int lane = tid & 63;
  const int l15  = lane & 15, quad = lane >> 4;
  const int n0   = w * 64;
  const int sw   = (l15 & 7) << 4;
  const char* Ab = (const char*)Av;

  auto stage = [&](int buf, int m0, int k0elt) {
#pragma unroll
    for (int j = 0; j < G; ++j) {
      int lin   = (j * 256 + tid) * 16;
      int row   = lin / ROWB;
      int inrow = lin - row * ROWB;
      int swz   = inrow ^ ((row & 7) << 4);
      int grow  = m0 + row;
      if (grow > M - 1) grow = M - 1;  // clamp (stores are guarded)
      gload_lds16(Ab + (size_t)grow * (K * EB) + (size_t)k0elt * EB + swz,
                  &smem[buf][lin]);
    }
  };

  auto store_tile = [&](f32x4 (&acc)[4][4], int m0) {
#pragma unroll
    for (int mtf = 0; mtf < 4; ++mtf) {
      int rl = m0 + mtf * 16 + quad * 4;
#pragma unroll
      for (int nt = 0; nt < 4; ++nt) {
        int col = n0 + nt * 16 + l15;
        float bv = bias ? bias[col] : 0.f;
#pragma unroll
        for (int ri = 0; ri < 4; ++ri) {
          int grow = rl + ri;
          if (grow < M) {
            size_t idx = (size_t)grow * Dh + col;
            float v = alpha * acc[mtf][nt][ri] + bv;
            if constexpr (OUT_BF16) ((__bf16*)Cv)[idx] = (__bf16)v;
            else                    ((float*)Cv)[idx]  = v;
          }
        }
      }
    }
  };

  if constexpr (!ABF16) {
    static_assert(K == 128, "f32 path expects K=128");
    int t = blockIdx.x;
    if (t >= mtiles) return;
    stage(0, t * 64, 0);
    // B is tiny (64 KB) and reused by every tile: load all frags once.
    bf16x8 bq[4][4];
#pragma unroll
    for (int ks = 0; ks < 4; ++ks)
#pragma unroll
      for (int nt = 0; nt < 4; ++nt)
        bq[ks][nt] = *(const bf16x8*)(
            Bt + (size_t)(n0 + nt * 16 + l15) * K + ks * 32 + quad * 8);
    int cur = 0;
    while (true) {
      int tn = t + gridDim.x;
      bool more = tn < mtiles;
      if (more) {
        stage(cur ^ 1, tn * 64, 0);
        asm volatile("s_waitcnt vmcnt(%0)" :: "n"(G) : "memory");
      } else {
        asm volatile("s_waitcnt vmcnt(0)" ::: "memory");
      }
      barrier_sync();
      const char* buf = smem[cur];
      f32x4 acc[4][4] = {};
      bf16x8 a[4][4];
#pragma unroll
      for (int mtf = 0; mtf < 4; ++mtf)
#pragma unroll
        for (int ks = 0; ks < 4; ++ks) {
          int y  = (mtf * 16 + l15) * 512 + ks * 128 + quad * 32;
          int ph = y ^ sw;
          f32x4 v0 = *(const f32x4*)(buf + ph);
          f32x4 v1 = *(const f32x4*)(buf + (ph ^ 16));
          bf16x8 tt;
          tt[0] = (__bf16)v0[0]; tt[1] = (__bf16)v0[1];
          tt[2] = (__bf16)v0[2]; tt[3] = (__bf16)v0[3];
          tt[4] = (__bf16)v1[0]; tt[5] = (__bf16)v1[1];
          tt[6] = (__bf16)v1[2]; tt[7] = (__bf16)v1[3];
          a[mtf][ks] = tt;
        }
#pragma unroll
      for (int mtf = 0; mtf < 4; ++mtf)
#pragma unroll
        for (int nt = 0; nt < 4; ++nt)
#pragma unroll
          for (int ks = 0; ks < 4; ++ks)
            acc[mtf][nt] = __builtin_amdgcn_mfma_f32_16x16x32_bf16(
                a[mtf][ks], bq[ks][nt], acc[mtf][nt], 0, 0, 0);
      store_tile(acc, t * 64);
      barrier_sync();
      if (!more) break;
      cur ^= 1; t = tn;
    }
  } else {
    static_assert(K == 1024, "bf16 path expects K=1024");
    int m0 = blockIdx.x * 64;
    stage(0, m0, 0);
    f32x4 acc[4][4] = {};
    int cur = 0;
#pragma unroll 1
    for (int kt = 0; kt < K / 128; ++kt) {
      bool more = kt < K / 128 - 1;
      if (more) {
        stage(cur ^ 1, m0, (kt + 1) * 128);
        asm volatile("s_waitcnt vmcnt(%0)" :: "n"(G) : "memory");
      } else {
        asm volatile("s_waitcnt vmcnt(0)" ::: "memory");
      }
      barrier_sync();
      const char* buf = smem[cur];
      bf16x8 bq[4][4];
#pragma unroll
      for (int ks = 0; ks < 4; ++ks)
#pragma unroll
        for (int nt = 0; nt < 4; ++nt)
          bq[ks][nt] = *(const bf16x8*)(
              Bt + (size_t)(n0 + nt * 16 + l15) * K + kt * 128 + ks * 32 + quad * 8);
      bf16x8 a[4][4];
#pragma unroll
      for (int mtf = 0; mtf < 4; ++mtf)
#pragma unroll
        for (int ks = 0; ks < 4; ++ks) {
          int y = (mtf * 16 + l15) * 256 + ks * 64 + quad * 16;
          a[mtf][ks] = *(const bf16x8*)(buf + (y ^ sw));
        }
#pragma unroll
      for (int mtf = 0; mtf < 4; ++mtf)
#pragma unroll
        for (int nt = 0; nt < 4; ++nt)
#pragma unroll
          for (int ks = 0; ks < 4; ++ks)
            acc[mtf][nt] = __builtin_amdgcn_mfma_f32_16x16x32_bf16(
                a[mtf][ks], bq[ks][nt], acc[mtf][nt], 0, 0, 0);
      barrier_sync();
      cur ^= 1;
    }
    store_tile(acc, m0);
  }
}

// ------------------------------------------------------------- CSR aggregate
__global__ __launch_bounds__(256) void aggregate4_kernel(
    const float* __restrict__ x, const __bf16* __restrict__ ew,
    const int* __restrict__ src, const int* __restrict__ rowptr,
    const int* __restrict__ eid, const float* __restrict__ ns,
    const float* __restrict__ nd, __bf16* __restrict__ agg4) {
  int g = blockIdx.x * 4 + (threadIdx.x >> 6);
  if (g >= RN) return;
  int r = g / Nn;
  int n = g - r * Nn;
  int lane = threadIdx.x & 63;
  int p0 = rowptr[g], p1 = rowptr[g + 1];
  const float* nsr = ns + (size_t)r * Nn;
  f32x4 acc = {0.f, 0.f, 0.f, 0.f};
  for (int p = p0; p < p1; p += 2) {
    int  geA  = eid[p];
    bool hasB = (p + 1 < p1);
    int  geB  = hasB ? eid[p + 1] : geA;
    int sA = src[geA];
    int sB = src[geB];
    float scA = nsr[sA];
    float scB = hasB ? nsr[sB] : 0.f;
    f32x4  xA = *(const f32x4*)(x + (size_t)sA * Dh + lane * 4);
    bf16x4 eA = *(const bf16x4*)(ew + (size_t)geA * Dh + lane * 4);
    f32x4  xB = *(const f32x4*)(x + (size_t)sB * Dh + lane * 4);
    bf16x4 eB = *(const bf16x4*)(ew + (size_t)geB * Dh + lane * 4);
    acc[0] += xA[0] * scA * (float)eA[0] + xB[0] * scB * (float)eB[0];
    acc[1] += xA[1] * scA * (float)eA[1] + xB[1] * scB * (float)eB[1];
    acc[2] += xA[2] * scA * (float)eA[2] + xB[2] * scB * (float)eB[2];
    acc[3] += xA[3] * scA * (float)eA[3] + xB[3] * scB * (float)eB[3];
  }
  float ndv = nd[g];
  bf16x4 o;
  o[0] = (__bf16)(acc[0] * ndv);
  o[1] = (__bf16)(acc[1] * ndv);
  o[2] = (__bf16)(acc[2] * ndv);
  o[3] = (__bf16)(acc[3] * ndv);
  *(bf16x4*)(agg4 + (size_t)n * (4 * Dh) + (size_t)r * Dh + lane * 4) = o;
}

// ------------------------------------- fallback atomic scatter (chunked ws)
__global__ __launch_bounds__(256) void edge_scatter_kernel(
    const float* __restrict__ x, const __bf16* __restrict__ ew,
    const int* __restrict__ src, const int* __restrict__ dst,
    const float* __restrict__ ns, const float* __restrict__ nd,
    float* __restrict__ aggf, int cnt) {
  int e = blockIdx.x * 4 + (threadIdx.x >> 6);
  if (e >= cnt) return;
  int lane = threadIdx.x & 63;
  int s = src[e], d = dst[e];
  float sc = ns[s] * nd[d];
  f32x4 xv = *(const f32x4*)(x + (size_t)s * Dh + lane * 4);
  bf16x4 ev = *(const bf16x4*)(ew + (size_t)e * Dh + lane * 4);
  float* ap = aggf + (size_t)d * Dh + lane * 4;
  atomicAdd(ap + 0, xv[0] * sc * (float)ev[0]);
  atomicAdd(ap + 1, xv[1] * sc * (float)ev[1]);
  atomicAdd(ap + 2, xv[2] * sc * (float)ev[2]);
  atomicAdd(ap + 3, xv[3] * sc * (float)ev[3]);
}

__global__ __launch_bounds__(256) void pack_agg_kernel(
    const float* __restrict__ aggf, __bf16* __restrict__ agg4, int r) {
  int i = blockIdx.x * 256 + threadIdx.x;
  if (i < Nn * 64) {
    int n = i >> 6;
    int c = (i & 63) * 4;
    f32x4 v = *(const f32x4*)(aggf + (size_t)n * Dh + c);
    bf16x4 o;
    o[0] = (__bf16)v[0]; o[1] = (__bf16)v[1];
    o[2] = (__bf16)v[2]; o[3] = (__bf16)v[3];
    *(bf16x4*)(agg4 + (size_t)n * (4 * Dh) + (size_t)r * Dh + c) = o;
  }
}

// ---------------------------------------------------------------- launch
extern "C" void kernel_launch(void* const* d_in, const int* in_sizes, int n_in,
                              void* d_out, int out_size, void* d_ws, size_t ws_size,
                              hipStream_t stream) {
  const float* node_feat  = (const float*)d_in[0];
  const float* edge_w_raw = (const float*)d_in[1];
  const int*   src        = (const int*)d_in[2];
  const int*   dst        = (const int*)d_in[3];
  const float* Wn = (const float*)d_in[4];
  const float* bn = (const float*)d_in[5];
  const float* Wr = (const float*)d_in[6];
  const float* br = (const float*)d_in[7];
  const float* W1 = (const float*)d_in[8];
  const float* b1 = (const float*)d_in[9];
  const float* W2 = (const float*)d_in[10];
  const float* b2 = (const float*)d_in[11];
  float* out = (float*)d_out;

  char* ws = (char*)d_ws;
  size_t off = 0;
  auto alloc = [&](size_t bytes) -> void* {
    void* p = ws + off;
    off += (bytes + 255) & ~(size_t)255;
    return p;
  };
  float*  ns     = (float*)alloc(sizeof(float) * RN);
  float*  nd     = (float*)alloc(sizeof(float) * RN);
  int*    rowptr = (int*)alloc(sizeof(int) * (RN + 1));
  int*    cursor = (int*)alloc(sizeof(int) * RN);
  int*    eid    = (int*)alloc(sizeof(int) * RE);
  int*    parts  = (int*)alloc(sizeof(int) * 512);
  float*  cb     = (float*)alloc(sizeof(float) * 2 * Dh);
  __bf16* BtWn   = (__bf16*)alloc(sizeof(__bf16) * (size_t)Din * Dh);
  __bf16* BtWr   = (__bf16*)alloc(sizeof(__bf16) * (size_t)Din * Dh);
  __bf16* BtW1   = (__bf16*)alloc(sizeof(__bf16) * (size_t)(4 * Dh) * Dh);
  __bf16* BtW2   = (__bf16*)alloc(sizeof(__bf16) * (size_t)(4 * Dh) * Dh);
  float*  x0     = (float*)alloc(sizeof(float) * (size_t)Nn * Dh);
  float*  h1     = (float*)alloc(sizeof(float) * (size_t)Nn * Dh);
  __bf16* agg4   = (__bf16*)alloc(sizeof(__bf16) * (size_t)Nn * 4 * Dh);
  size_t fixed = off;
  size_t ew_full_bytes = (size_t)RE * Dh * 2;
  bool full = (fixed + ew_full_bytes) <= ws_size;
  __bf16* ewb  = nullptr;
  float*  aggf = nullptr;
  int CH = Ee;
  if (full) {
    ewb = (__bf16*)alloc(ew_full_bytes);
  } else {
    aggf = (float*)alloc(sizeof(float) * (size_t)Nn * Dh);
    size_t avail = ws_size > off ? ws_size - off : 0;
    size_t ch = avail / ((size_t)Dh * 2);
    ch = (ch / 512) * 512;
    if (ch > (size_t)Ee) ch = (size_t)Ee;
    if (ch < 512) ch = 512;
    CH = (int)ch;
    ewb = (__bf16*)alloc((size_t)CH * Dh * 2);
  }

  // degrees live temporarily in agg4 (3.2 MB << 204.8 MB)
  int* dego = (int*)agg4;
  int* degi = dego + RN;
  hipMemsetAsync(dego, 0, sizeof(int) * 2 * (size_t)RN, stream);
  count_deg_kernel<<<(RE + 255) / 256, 256, 0, stream>>>(src, dst, dego, degi);
  norms_kernel<<<(RN + 255) / 256, 256, 0, stream>>>(dego, degi, ns, nd);

  // CSR build (shared by both layers)
  int nchunks = (RN + 1023) / 1024;  // 391
  scan1_kernel<<<nchunks, 256, 0, stream>>>(degi, rowptr, parts, RN);
  scan2_kernel<<<1, 256, 0, stream>>>(parts, nchunks);
  scan3_kernel<<<(RN + 255) / 256, 256, 0, stream>>>(rowptr, parts, RN);
  hipMemcpyAsync(cursor, rowptr, sizeof(int) * RN, hipMemcpyDeviceToDevice, stream);
  fill_eid_kernel<<<(RE + 255) / 256, 256, 0, stream>>>(dst, cursor, eid);

  // small prep: combined biases + weight transposes (bf16 [256][K])
  bias_combine_kernel<<<1, 256, 0, stream>>>(b1, b2, cb);
  transpose_bf16_kernel<<<dim3(Din / 32, Dh / 32), 256, 0, stream>>>(Wn, BtWn, Din);
  transpose_bf16_kernel<<<dim3(Din / 32, Dh / 32), 256, 0, stream>>>(Wr, BtWr, Din);
  transpose_bf16_kernel<<<dim3(4 * Dh / 32, Dh / 32), 256, 0, stream>>>(W1, BtW1, 4 * Dh);
  transpose_bf16_kernel<<<dim3(4 * Dh / 32, Dh / 32), 256, 0, stream>>>(W2, BtW2, 4 * Dh);

  // x0 = node_feat @ Wn + bn
  {
    int mt = (Nn + 63) / 64;
    int g = mt < 512 ? mt : 512;
    gemm_pipe<Din, false, false><<<g, 256, 0, stream>>>(
        node_feat, BtWn, x0, bn, 1.0f, Nn, mt);
  }

  // ew = edge_w_raw @ Wr + br  (all 4 relations in one M=800000 pass)
  if (full) {
    int mt = RE / 64;
    gemm_pipe<Din, false, true><<<512, 256, 0, stream>>>(
        edge_w_raw, BtWr, ewb, br, 1.0f, RE, mt);
  }

  for (int layer = 0; layer < 2; ++layer) {
    const float*  x   = layer ? h1 : x0;
    float*        o   = layer ? out : h1;
    const __bf16* Bt  = layer ? BtW2 : BtW1;
    const float*  cbl = cb + layer * Dh;
    if (full) {
      aggregate4_kernel<<<(RN + 3) / 4, 256, 0, stream>>>(
          x, ewb, src, rowptr, eid, ns, nd, agg4);
    } else {
      for (int r = 0; r < Rr; ++r) {
        hipMemsetAsync(aggf, 0, sizeof(float) * (size_t)Nn * Dh, stream);
        for (int c0 = 0; c0 < Ee; c0 += CH) {
          int cnt = (Ee - c0 < CH) ? (Ee - c0) : CH;
          int mt = (cnt + 63) / 64;
          int g = mt < 512 ? mt : 512;
          gemm_pipe<Din, false, true><<<g, 256, 0, stream>>>(
              edge_w_raw + ((size_t)r * Ee + c0) * Din, BtWr, ewb, br, 1.0f, cnt, mt);
          edge_scatter_kernel<<<(cnt + 3) / 4, 256, 0, stream>>>(
              x, ewb, src + (size_t)r * Ee + c0, dst + (size_t)r * Ee + c0,
              ns + (size_t)r * Nn, nd + (size_t)r * Nn, aggf, cnt);
        }
        pack_agg_kernel<<<(Nn * 64 + 255) / 256, 256, 0, stream>>>(aggf, agg4, r);
      }
    }
    // o = 0.25 * agg4 @ [W_r stacked] + 0.25*sum_r b_r   (single K=1024 GEMM)
    gemm_pipe<4 * Dh, true, false><<<(Nn + 63) / 64, 256, 0, stream>>>(
        agg4, Bt, o, cbl, 0.25f, Nn, (Nn + 63) / 64);
  }
}